// Round 3
// baseline (596.684 us; speedup 1.0000x reference)
//
#include <hip/hip_runtime.h>

#define HW_N 1048576
#define C_IN 64
#define K_CLS 4096
#define H1_N 256
#define NCLS_N 16
#define RG_N 32                 // row groups
#define ROWS_PER_BLK (HW_N / RG_N)   // 32768
#define NE 8                    // cluster eighths
#define CL_SUB 512              // clusters per eighth
#define WL_CAP 4608             // worklist capacity (exp 4096, sigma~60)

__device__ __forceinline__ float silu_f(float x) {
  return x / (1.0f + expf(-x));
}

// Degree-3 B-spline bases on the uniform grid g[j] = 0.4*(j-3) - 1, j=0..11.
__device__ __forceinline__ void bspline8(float x, float* b) {
  float t[11];
#pragma unroll
  for (int j = 0; j < 11; ++j) {
    float g0 = 0.4f * (float)(j - 3) - 1.0f;
    float g1 = 0.4f * (float)(j - 2) - 1.0f;
    t[j] = (x >= g0 && x < g1) ? 1.0f : 0.0f;
  }
#pragma unroll
  for (int k = 1; k <= 3; ++k) {
#pragma unroll 10
    for (int j = 0; j + k < 11; ++j) {
      float gj   = 0.4f * (float)(j - 3) - 1.0f;
      float gj1  = 0.4f * (float)(j - 2) - 1.0f;
      float gjk  = 0.4f * (float)(j + k - 3) - 1.0f;
      float gjk1 = 0.4f * (float)(j + k - 2) - 1.0f;
      float left  = (x - gj) / (gjk - gj);
      float right = (gjk1 - x) / (gjk1 - gj1);
      t[j] = left * t[j] + right * t[j + 1];
    }
  }
#pragma unroll
  for (int g = 0; g < 8; ++g) b[g] = t[g];
}

// ---------------- Kernel 1: partial segment sums + counts ----------------
// Grid = NE eighths x RG_N row-groups = 256 blocks x 1024 threads.
// Pass 1: build worklist of matching rows (lane-parallel append).
// Pass 2: consume worklist, 8 coalesced 256-B row loads in flight per wave.
__global__ __launch_bounds__(1024) void segsum_part(
    const float* __restrict__ x, const int* __restrict__ cls,
    float* __restrict__ partials, int* __restrict__ cntpart) {
  __shared__ float hist[CL_SUB][C_IN];   // 128 KB, bank = f%32 -> conflict-free
  __shared__ int   wl[WL_CAP];           // 18 KB packed (roff<<9 | cl)
  __shared__ int   cnthist[CL_SUB];      // 2 KB
  __shared__ int   wl_n;

  int b = blockIdx.x;
  int e  = b >> 5;       // cluster eighth
  int rg = b & 31;       // row group
  int tid = threadIdx.x;
  int wave = tid >> 6, lane = tid & 63;

  float* hflat = &hist[0][0];
  for (int p = tid; p < CL_SUB * C_IN; p += 1024) hflat[p] = 0.0f;
  for (int p = tid; p < CL_SUB; p += 1024) cnthist[p] = 0;
  if (tid == 0) wl_n = 0;
  __syncthreads();

  // ---- pass 1: scan cls, build worklist ----
  int wrow0 = wave * 2048;  // this wave's rows within the block (2048 rows)
  int blockrow0 = rg * ROWS_PER_BLK;
  for (int ch = 0; ch < 32; ++ch) {
    int roff0 = wrow0 + ch * 64;                 // row offset within block
    int myc = cls[blockrow0 + roff0 + lane];
    bool match = ((myc >> 9) == e);
    unsigned long long mask = __ballot(match);
    if (mask) {
      int nmatch = __popcll(mask);
      int base = 0;
      if (lane == 0) base = atomicAdd(&wl_n, nmatch);
      base = __shfl(base, 0);
      if (match) {
        int cl = myc & (CL_SUB - 1);
        int pos = base + __popcll(mask & ((1ull << lane) - 1ull));
        if (pos < WL_CAP) wl[pos] = ((roff0 + lane) << 9) | cl;
        atomicAdd(&cnthist[cl], 1);
      }
    }
  }
  __syncthreads();

  // ---- pass 2: gather rows (coalesced) and accumulate ----
  int n = wl_n < WL_CAP ? wl_n : WL_CAP;
  for (int i0 = wave * 8; i0 < n; i0 += 16 * 8) {
    int cnt8 = n - i0; cnt8 = cnt8 > 8 ? 8 : cnt8;
    int pk[8]; float v[8];
#pragma unroll
    for (int j = 0; j < 8; ++j) {
      if (j < cnt8) {
        pk[j] = wl[i0 + j];
        v[j] = x[((size_t)blockrow0 + (pk[j] >> 9)) * C_IN + lane];
      }
    }
#pragma unroll
    for (int j = 0; j < 8; ++j)
      if (j < cnt8) atomicAdd(&hist[pk[j] & (CL_SUB - 1)][lane], v[j]);
  }
  __syncthreads();

  // ---- flush ----
  float* dst = partials + (size_t)b * (CL_SUB * C_IN);
  for (int p = tid; p < CL_SUB * C_IN; p += 1024) dst[p] = hflat[p];
  int* cdst = cntpart + b * CL_SUB;
  for (int p = tid; p < CL_SUB; p += 1024) cdst[p] = cnthist[p];
}

// partials[(e*32+rg)][cl][f] -> sums[c][f]
__global__ __launch_bounds__(256) void segsum_reduce(
    const float* __restrict__ partials, float* __restrict__ sums) {
  int t = blockIdx.x * 256 + threadIdx.x;  // t = c*64 + f
  int f = t & 63;
  int c = t >> 6;
  int e = c >> 9, cl = c & (CL_SUB - 1);
  const float* p = partials + (size_t)(e * 32) * (CL_SUB * C_IN) + cl * C_IN + f;
  float s = 0.0f;
#pragma unroll
  for (int rg = 0; rg < RG_N; ++rg) s += p[(size_t)rg * (CL_SUB * C_IN)];
  sums[c * C_IN + f] = s;
}

__global__ __launch_bounds__(256) void cnt_reduce2(
    const int* __restrict__ cntpart, int* __restrict__ cnt) {
  int c = blockIdx.x * 256 + threadIdx.x;
  int e = c >> 9, cl = c & (CL_SUB - 1);
  int s = 0;
#pragma unroll
  for (int rg = 0; rg < RG_N; ++rg) s += cntpart[(e * 32 + rg) * CL_SUB + cl];
  cnt[c] = s;
}

// ---------------- Kernel 2: mean + KAN layer 1 (64 -> 256) ----------------
__global__ __launch_bounds__(256) void kan1(
    const float* __restrict__ sums, const int* __restrict__ cnt,
    const float* __restrict__ bw1, const float* __restrict__ sw1,
    const float* __restrict__ sc1, float* __restrict__ h) {
  __shared__ float s_silu[8][64];      // 2 KB
  __shared__ float s_bases[8][64][8];  // 16 KB
  int row0 = blockIdx.x * 8;
  int tid = threadIdx.x;

  for (int p = tid; p < 8 * 64; p += 256) {
    int r = p >> 6, i = p & 63;
    float c = fmaxf((float)cnt[row0 + r], 1.0f);
    float xv = sums[(row0 + r) * C_IN + i] / c;
    s_silu[r][i] = silu_f(xv);
    float b[8];
    bspline8(xv, b);
    float4* dst = (float4*)&s_bases[r][i][0];
    dst[0] = make_float4(b[0], b[1], b[2], b[3]);
    dst[1] = make_float4(b[4], b[5], b[6], b[7]);
  }
  __syncthreads();

  int o = tid;
  float acc[8];
#pragma unroll
  for (int r = 0; r < 8; ++r) acc[r] = 0.0f;

  for (int i = 0; i < C_IN; ++i) {
    float wb  = bw1[o * C_IN + i];
    float wsc = sc1[o * C_IN + i];
    const float4* wp = (const float4*)&sw1[(o * C_IN + i) * 8];
    float4 w0 = wp[0], w1 = wp[1];
    w0.x *= wsc; w0.y *= wsc; w0.z *= wsc; w0.w *= wsc;
    w1.x *= wsc; w1.y *= wsc; w1.z *= wsc; w1.w *= wsc;
#pragma unroll
    for (int r = 0; r < 8; ++r) {
      float sv = s_silu[r][i];
      const float4* bp = (const float4*)&s_bases[r][i][0];
      float4 b0 = bp[0], b1 = bp[1];
      float a = acc[r];
      a = fmaf(sv, wb, a);
      a = fmaf(b0.x, w0.x, a); a = fmaf(b0.y, w0.y, a);
      a = fmaf(b0.z, w0.z, a); a = fmaf(b0.w, w0.w, a);
      a = fmaf(b1.x, w1.x, a); a = fmaf(b1.y, w1.y, a);
      a = fmaf(b1.z, w1.z, a); a = fmaf(b1.w, w1.w, a);
      acc[r] = a;
    }
  }
#pragma unroll
  for (int r = 0; r < 8; ++r) h[(row0 + r) * H1_N + o] = acc[r];
}

// ---------------- Kernel 3: KAN layer 2 (256 -> 16) ----------------
__global__ __launch_bounds__(256) void kan2(
    const float* __restrict__ h,
    const float* __restrict__ bw2, const float* __restrict__ sw2,
    const float* __restrict__ sc2, float* __restrict__ out) {
  __shared__ float s_silu[16][65];
  __shared__ float s_bases[16][516];
  int row0 = blockIdx.x * 16;
  int tid = threadIdx.x;
  int o = tid & 15, rr = tid >> 4;
  float acc = 0.0f;

  for (int ic0 = 0; ic0 < H1_N; ic0 += 64) {
    for (int p = tid; p < 16 * 64; p += 256) {
      int r = p >> 6, i = p & 63;
      float xv = h[(row0 + r) * H1_N + ic0 + i];
      s_silu[r][i] = silu_f(xv);
      float b[8];
      bspline8(xv, b);
      float4* dst = (float4*)&s_bases[r][i * 8];
      dst[0] = make_float4(b[0], b[1], b[2], b[3]);
      dst[1] = make_float4(b[4], b[5], b[6], b[7]);
    }
    __syncthreads();

    for (int i = 0; i < 64; ++i) {
      int gi = ic0 + i;
      float wb  = bw2[o * H1_N + gi];
      float wsc = sc2[o * H1_N + gi];
      const float4* wp = (const float4*)&sw2[(o * H1_N + gi) * 8];
      float4 w0 = wp[0], w1 = wp[1];
      float sv = s_silu[rr][i];
      const float4* bp = (const float4*)&s_bases[rr][i * 8];
      float4 b0 = bp[0], b1 = bp[1];
      float sp = b0.x * w0.x + b0.y * w0.y + b0.z * w0.z + b0.w * w0.w
               + b1.x * w1.x + b1.y * w1.y + b1.z * w1.z + b1.w * w1.w;
      acc = fmaf(sv, wb, acc);
      acc = fmaf(sp, wsc, acc);
    }
    __syncthreads();
  }
  out[(row0 + rr) * NCLS_N + o] = acc;
}

extern "C" void kernel_launch(void* const* d_in, const int* in_sizes, int n_in,
                              void* d_out, int out_size, void* d_ws, size_t ws_size,
                              hipStream_t stream) {
  const float* x   = (const float*)d_in[0];
  const int*   cls = (const int*)d_in[1];
  const float* bw1 = (const float*)d_in[2];
  const float* sw1 = (const float*)d_in[3];
  const float* sc1 = (const float*)d_in[4];
  const float* bw2 = (const float*)d_in[5];
  const float* sw2 = (const float*)d_in[6];
  const float* sc2 = (const float*)d_in[7];
  float* out = (float*)d_out;

  float* partials = (float*)d_ws;                          // 256*512*64 f = 32 MB
  int*   cntpart = (int*)(partials + 256 * CL_SUB * C_IN); // 256*512 i = 512 KB
  float* sums = (float*)(cntpart + 256 * CL_SUB);          // 1 MB
  int*   cnt  = (int*)(sums + K_CLS * C_IN);               // 16 KB
  float* h    = (float*)(cnt + K_CLS);                     // 4 MB

  segsum_part<<<NE * RG_N, 1024, 0, stream>>>(x, cls, partials, cntpart);
  segsum_reduce<<<(K_CLS * C_IN) / 256, 256, 0, stream>>>(partials, sums);
  cnt_reduce2<<<K_CLS / 256, 256, 0, stream>>>(cntpart, cnt);
  kan1<<<K_CLS / 8, 256, 0, stream>>>(sums, cnt, bw1, sw1, sc1, h);
  kan2<<<K_CLS / 16, 256, 0, stream>>>(h, bw2, sw2, sc2, out);
}

// Round 4
// 573.548 us; speedup vs baseline: 1.0403x; 1.0403x over previous
//
#include <hip/hip_runtime.h>

#define HW_N 1048576
#define C_IN 64
#define K_CLS 4096
#define H1_N 256
#define NCLS_N 16
#define CNT_BLOCKS 64
#define ROWS_PER_CNT (HW_N / CNT_BLOCKS)   // 16384
#define GATHER_POS 4096                    // sorted positions per gather block
#define RELC 64                            // rel-cluster window (worst case ~24)

__device__ __forceinline__ float silu_f(float x) {
  return x / (1.0f + expf(-x));
}

// Degree-3 B-spline bases on the uniform grid g[j] = 0.4*(j-3) - 1, j=0..11.
__device__ __forceinline__ void bspline8(float x, float* b) {
  float t[11];
#pragma unroll
  for (int j = 0; j < 11; ++j) {
    float g0 = 0.4f * (float)(j - 3) - 1.0f;
    float g1 = 0.4f * (float)(j - 2) - 1.0f;
    t[j] = (x >= g0 && x < g1) ? 1.0f : 0.0f;
  }
#pragma unroll
  for (int k = 1; k <= 3; ++k) {
#pragma unroll 10
    for (int j = 0; j + k < 11; ++j) {
      float gj   = 0.4f * (float)(j - 3) - 1.0f;
      float gj1  = 0.4f * (float)(j - 2) - 1.0f;
      float gjk  = 0.4f * (float)(j + k - 3) - 1.0f;
      float gjk1 = 0.4f * (float)(j + k - 2) - 1.0f;
      float left  = (x - gj) / (gjk - gj);
      float right = (gjk1 - x) / (gjk1 - gj1);
      t[j] = left * t[j] + right * t[j + 1];
    }
  }
#pragma unroll
  for (int g = 0; g < 8; ++g) b[g] = t[g];
}

// ---- Stage A: per-block cluster histograms of cls -> bcnt[b][c] ----
__global__ __launch_bounds__(1024) void segcnt(
    const int* __restrict__ cls, int* __restrict__ bcnt) {
  __shared__ int chist[K_CLS];  // 16 KB
  int tid = threadIdx.x, b = blockIdx.x;
  for (int p = tid; p < K_CLS; p += 1024) chist[p] = 0;
  __syncthreads();
  int r0 = b * ROWS_PER_CNT;
  for (int r = r0 + tid; r < r0 + ROWS_PER_CNT; r += 1024)
    atomicAdd(&chist[cls[r]], 1);
  __syncthreads();
  int* dst = bcnt + b * K_CLS;
  for (int p = tid; p < K_CLS; p += 1024) dst[p] = chist[p];
}

// ---- Stage B1: per-cluster exclusive prefix over blocks ----
// bboff[b][c] = sum_{b'<b} bcnt[b'][c];  tot[c] = sum_b bcnt[b][c]
__global__ __launch_bounds__(256) void scan_blocks(
    const int* __restrict__ bcnt, int* __restrict__ bboff, int* __restrict__ tot) {
  int c = blockIdx.x * 256 + threadIdx.x;
  int run = 0;
#pragma unroll
  for (int b = 0; b < CNT_BLOCKS; ++b) {
    int v = bcnt[b * K_CLS + c];
    bboff[b * K_CLS + c] = run;
    run += v;
  }
  tot[c] = run;
}

// ---- Stage B2: exclusive scan over 4096 cluster totals -> base, cnt ----
__global__ __launch_bounds__(1024) void scan_clusters(
    const int* __restrict__ tot, int* __restrict__ base_, int* __restrict__ cnt) {
  __shared__ int wsum[16];
  int t = threadIdx.x;
  int c0 = t * 4;
  int v0 = tot[c0], v1 = tot[c0 + 1], v2 = tot[c0 + 2], v3 = tot[c0 + 3];
  int s = v0 + v1 + v2 + v3;
  int lane = t & 63, wave = t >> 6;
  int inc = s;
#pragma unroll
  for (int d = 1; d < 64; d <<= 1) {
    int o = __shfl_up(inc, d);
    if (lane >= d) inc += o;
  }
  if (lane == 63) wsum[wave] = inc;
  __syncthreads();
  if (t == 0) {
    int run = 0;
#pragma unroll
    for (int w = 0; w < 16; ++w) { int x_ = wsum[w]; wsum[w] = run; run += x_; }
  }
  __syncthreads();
  int excl = wsum[wave] + inc - s;
  base_[c0]     = excl;
  base_[c0 + 1] = excl + v0;
  base_[c0 + 2] = excl + v0 + v1;
  base_[c0 + 3] = excl + v0 + v1 + v2;
  cnt[c0] = v0; cnt[c0 + 1] = v1; cnt[c0 + 2] = v2; cnt[c0 + 3] = v3;
}

// ---- Stage C: scatter packed keys (row<<12 | cls) into sorted order ----
__global__ __launch_bounds__(1024) void scatter_idx(
    const int* __restrict__ cls, const int* __restrict__ bboff,
    const int* __restrict__ base_, int* __restrict__ spk) {
  __shared__ int lhist[K_CLS];  // 16 KB
  int b = blockIdx.x, tid = threadIdx.x;
  for (int c = tid; c < K_CLS; c += 1024)
    lhist[c] = bboff[b * K_CLS + c] + base_[c];
  __syncthreads();
  int r0 = b * ROWS_PER_CNT;
  for (int r = r0 + tid; r < r0 + ROWS_PER_CNT; r += 1024) {
    int c = cls[r];
    int pos = atomicAdd(&lhist[c], 1);
    spk[pos] = (r << 12) | c;
  }
}

// ---- Stage D: gather rows in sorted order, accumulate into sums ----
// 256 blocks x 1024 thr; block owns sorted window [blk*4096, +4096).
// Window spans ~16-24 clusters -> hist[64][64] = 16 KB; LDS total 33 KB
// -> 2 blocks/CU, 8 waves/SIMD. Branch-free 8-deep pipelined row gathers.
__global__ __launch_bounds__(1024) void gather_sum(
    const float* __restrict__ x, const int* __restrict__ spk,
    float* __restrict__ sums) {
  __shared__ int   sidx[GATHER_POS];     // 16 KB
  __shared__ float hist[RELC][C_IN];     // 16 KB
  int tid = threadIdx.x;
  int wave = tid >> 6, f = tid & 63;
  const int* src = spk + blockIdx.x * GATHER_POS;
  for (int p = tid; p < GATHER_POS; p += 1024) sidx[p] = src[p];
  float* hflat = &hist[0][0];
  for (int p = tid; p < RELC * C_IN; p += 1024) hflat[p] = 0.0f;
  __syncthreads();
  int cstart = sidx[0] & 4095;
  int clast  = sidx[GATHER_POS - 1] & 4095;

  int p0 = wave * 256;
#pragma unroll 1
  for (int it = 0; it < 32; ++it) {
    int pk[8]; float v[8];
#pragma unroll
    for (int j = 0; j < 8; ++j) pk[j] = sidx[p0 + it * 8 + j];
#pragma unroll
    for (int j = 0; j < 8; ++j)
      v[j] = x[(size_t)((unsigned)pk[j] >> 12) * C_IN + f];
#pragma unroll
    for (int j = 0; j < 8; ++j) {
      int rc = (pk[j] & 4095) - cstart;   // wave-uniform
      if (rc < RELC) atomicAdd(&hist[rc][f], v[j]);
      else unsafeAtomicAdd(&sums[(size_t)(pk[j] & 4095) * C_IN + f], v[j]);
    }
  }
  __syncthreads();

  int nrel = clast - cstart + 1;
  if (nrel > RELC) nrel = RELC;
  for (int t = tid; t < nrel * C_IN; t += 1024) {
    int rc = t >> 6, ff = t & 63;
    unsafeAtomicAdd(&sums[(size_t)(cstart + rc) * C_IN + ff], hist[rc][ff]);
  }
}

// ---------------- KAN layer 1 (64 -> 256) ----------------
__global__ __launch_bounds__(256) void kan1(
    const float* __restrict__ sums, const int* __restrict__ cnt,
    const float* __restrict__ bw1, const float* __restrict__ sw1,
    const float* __restrict__ sc1, float* __restrict__ h) {
  __shared__ float s_silu[8][64];      // 2 KB
  __shared__ float s_bases[8][64][8];  // 16 KB
  int row0 = blockIdx.x * 8;
  int tid = threadIdx.x;

  for (int p = tid; p < 8 * 64; p += 256) {
    int r = p >> 6, i = p & 63;
    float c = fmaxf((float)cnt[row0 + r], 1.0f);
    float xv = sums[(row0 + r) * C_IN + i] / c;
    s_silu[r][i] = silu_f(xv);
    float b[8];
    bspline8(xv, b);
    float4* dst = (float4*)&s_bases[r][i][0];
    dst[0] = make_float4(b[0], b[1], b[2], b[3]);
    dst[1] = make_float4(b[4], b[5], b[6], b[7]);
  }
  __syncthreads();

  int o = tid;
  float acc[8];
#pragma unroll
  for (int r = 0; r < 8; ++r) acc[r] = 0.0f;

  for (int i = 0; i < C_IN; ++i) {
    float wb  = bw1[o * C_IN + i];
    float wsc = sc1[o * C_IN + i];
    const float4* wp = (const float4*)&sw1[(o * C_IN + i) * 8];
    float4 w0 = wp[0], w1 = wp[1];
    w0.x *= wsc; w0.y *= wsc; w0.z *= wsc; w0.w *= wsc;
    w1.x *= wsc; w1.y *= wsc; w1.z *= wsc; w1.w *= wsc;
#pragma unroll
    for (int r = 0; r < 8; ++r) {
      float sv = s_silu[r][i];
      const float4* bp = (const float4*)&s_bases[r][i][0];
      float4 b0 = bp[0], b1 = bp[1];
      float a = acc[r];
      a = fmaf(sv, wb, a);
      a = fmaf(b0.x, w0.x, a); a = fmaf(b0.y, w0.y, a);
      a = fmaf(b0.z, w0.z, a); a = fmaf(b0.w, w0.w, a);
      a = fmaf(b1.x, w1.x, a); a = fmaf(b1.y, w1.y, a);
      a = fmaf(b1.z, w1.z, a); a = fmaf(b1.w, w1.w, a);
      acc[r] = a;
    }
  }
#pragma unroll
  for (int r = 0; r < 8; ++r) h[(row0 + r) * H1_N + o] = acc[r];
}

// ---------------- KAN layer 2 (256 -> 16) ----------------
__global__ __launch_bounds__(256) void kan2(
    const float* __restrict__ h,
    const float* __restrict__ bw2, const float* __restrict__ sw2,
    const float* __restrict__ sc2, float* __restrict__ out) {
  __shared__ float s_silu[16][65];
  __shared__ float s_bases[16][516];
  int row0 = blockIdx.x * 16;
  int tid = threadIdx.x;
  int o = tid & 15, rr = tid >> 4;
  float acc = 0.0f;

  for (int ic0 = 0; ic0 < H1_N; ic0 += 64) {
    for (int p = tid; p < 16 * 64; p += 256) {
      int r = p >> 6, i = p & 63;
      float xv = h[(row0 + r) * H1_N + ic0 + i];
      s_silu[r][i] = silu_f(xv);
      float b[8];
      bspline8(xv, b);
      float4* dst = (float4*)&s_bases[r][i * 8];
      dst[0] = make_float4(b[0], b[1], b[2], b[3]);
      dst[1] = make_float4(b[4], b[5], b[6], b[7]);
    }
    __syncthreads();

    for (int i = 0; i < 64; ++i) {
      int gi = ic0 + i;
      float wb  = bw2[o * H1_N + gi];
      float wsc = sc2[o * H1_N + gi];
      const float4* wp = (const float4*)&sw2[(o * H1_N + gi) * 8];
      float4 w0 = wp[0], w1 = wp[1];
      float sv = s_silu[rr][i];
      const float4* bp = (const float4*)&s_bases[rr][i * 8];
      float4 b0 = bp[0], b1 = bp[1];
      float sp = b0.x * w0.x + b0.y * w0.y + b0.z * w0.z + b0.w * w0.w
               + b1.x * w1.x + b1.y * w1.y + b1.z * w1.z + b1.w * w1.w;
      acc = fmaf(sv, wb, acc);
      acc = fmaf(sp, wsc, acc);
    }
    __syncthreads();
  }
  out[(row0 + rr) * NCLS_N + o] = acc;
}

extern "C" void kernel_launch(void* const* d_in, const int* in_sizes, int n_in,
                              void* d_out, int out_size, void* d_ws, size_t ws_size,
                              hipStream_t stream) {
  const float* x   = (const float*)d_in[0];
  const int*   cls = (const int*)d_in[1];
  const float* bw1 = (const float*)d_in[2];
  const float* sw1 = (const float*)d_in[3];
  const float* sc1 = (const float*)d_in[4];
  const float* bw2 = (const float*)d_in[5];
  const float* sw2 = (const float*)d_in[6];
  const float* sc2 = (const float*)d_in[7];
  float* out = (float*)d_out;

  float* sums  = (float*)d_ws;                 // 4096*64 f   (1 MB)
  int*   cnt   = (int*)(sums + K_CLS * C_IN);  // 4096
  int*   bcnt  = cnt + K_CLS;                  // 64*4096     (1 MB)
  int*   bboff = bcnt + CNT_BLOCKS * K_CLS;    // 64*4096     (1 MB)
  int*   tot   = bboff + CNT_BLOCKS * K_CLS;   // 4096
  int*   base_ = tot + K_CLS;                  // 4096
  int*   spk   = base_ + K_CLS;                // 1048576     (4 MB)
  float* h     = (float*)(spk + HW_N);         // 4096*256 f  (4 MB)

  hipMemsetAsync(sums, 0, K_CLS * C_IN * sizeof(float), stream);

  segcnt<<<CNT_BLOCKS, 1024, 0, stream>>>(cls, bcnt);
  scan_blocks<<<K_CLS / 256, 256, 0, stream>>>(bcnt, bboff, tot);
  scan_clusters<<<1, 1024, 0, stream>>>(tot, base_, cnt);
  scatter_idx<<<CNT_BLOCKS, 1024, 0, stream>>>(cls, bboff, base_, spk);
  gather_sum<<<HW_N / GATHER_POS, 1024, 0, stream>>>(x, spk, sums);
  kan1<<<K_CLS / 8, 256, 0, stream>>>(sums, cnt, bw1, sw1, sc1, h);
  kan2<<<K_CLS / 16, 256, 0, stream>>>(h, bw2, sw2, sc2, out);
}